// Round 1
// baseline (1221.968 us; speedup 1.0000x reference)
//
#include <hip/hip_runtime.h>

#define LLEN 131072
#define CDIM 64
#define NB 4
#define TP 62            // output positions per 64-wide window (1 halo each side)
#define TILES 2115       // 2115*62 = 131130 >= 131072
#define NCH_A 3
#define BLKA 705         // 705*3 = 2115
#define NCH_C 3
#define BLKC 705
#define QS_PITCH 68

// ---------------- prep: transposed weight tables (wT[ci][ch]) ----------------
__global__ void prep_kernel(const float* __restrict__ w_q,
                            const float* __restrict__ w_kv,
                            float* __restrict__ wqT, float* __restrict__ wkT,
                            float* __restrict__ wvT) {
  const int idx = blockIdx.x * 256 + threadIdx.x;  // 0..4095
  const int ci = idx >> 6, ch = idx & 63;
  wqT[ci * 64 + ch] = w_q[ch * 64 + ci];
  wkT[ci * 64 + ch] = w_kv[ch * 64 + ci];
  wvT[ci * 64 + ch] = w_kv[(64 + ch) * 64 + ci];
}

// ---------------- Kernel A: qk GEMM (reg-pipelined x, fused 32-ch acc)
// ---------------- -> shuffle dwconv -> Gram (8x4 reg tile) + norms ----------
__global__ __launch_bounds__(256, 4) void qk_gram_kernel(
    const float* __restrict__ x, const float* __restrict__ wqT,
    const float* __restrict__ wkT, const float* __restrict__ w_q_dw,
    const float* __restrict__ w_kv_dw, float* __restrict__ G,
    float* __restrict__ nq, float* __restrict__ nk) {
  __shared__ __attribute__((aligned(16))) float smem[2 * TP * QS_PITCH]; // 33.7 KB
  float* q_s = smem;                       // [l][c], pitch 68
  float* k_s = smem + TP * QS_PITCH;

  const int tid  = threadIdx.x;
  const int lane = tid & 63;
  const int wv   = __builtin_amdgcn_readfirstlane(threadIdx.x >> 6);
  const int b    = blockIdx.y;

  const float* xb  = x + (size_t)b * CDIM * LLEN;
  const float* wT  = (wv < 2) ? wqT : wkT;
  const float* wdw = (wv < 2) ? w_q_dw : w_kv_dw;  // k = rows 0..63 of w_kv_dw
  const int chbase = (wv & 1) * 32;
  float* dst_s = (wv < 2) ? q_s : k_s;

  const int c0 = (tid & 7) * 8;
  const int d0 = ((tid >> 3) & 15) * 4;
  const int lbeg = (tid >> 7) ? 31 : 0;
  const int lend = (tid >> 7) ? 62 : 31;

  float gacc[32];
#pragma unroll
  for (int i = 0; i < 32; ++i) gacc[i] = 0.f;
  float nrm = 0.f;

  for (int ck = 0; ck < NCH_A; ++ck) {
    const int p0 = (blockIdx.x * NCH_A + ck) * TP;
    const int p  = p0 - 1 + lane;                 // window position for this lane
    const int pc = min(max(p, 0), LLEN - 1);
    const bool pvalid = (p >= 0) && (p < LLEN);
    const float* xp = xb + pc;

    // ---- GEMM: 32 output channels per wave, single sweep over 64 in-channels
    // x preloaded in 8-deep double-buffered register chunks (static indexing).
    float acc[32];
#pragma unroll
    for (int j = 0; j < 32; ++j) acc[j] = 0.f;

    float xv[2][8];
#pragma unroll
    for (int i = 0; i < 8; ++i) xv[0][i] = xp[(size_t)i * LLEN];
#pragma unroll
    for (int chunk = 0; chunk < 8; ++chunk) {
      const int cur = chunk & 1;
      const int nxt = cur ^ 1;
      if (chunk < 7) {
#pragma unroll
        for (int i = 0; i < 8; ++i)
          xv[nxt][i] = xp[(size_t)((chunk + 1) * 8 + i) * LLEN];
      }
#pragma unroll
      for (int i = 0; i < 8; ++i) {
        const float xval = xv[cur][i];
        const float* wrow = wT + (chunk * 8 + i) * 64 + chbase;  // s_load_dwordx16 x2
#pragma unroll
        for (int j = 0; j < 32; ++j) acc[j] = fmaf(wrow[j], xval, acc[j]);
      }
    }
#pragma unroll
    for (int j = 0; j < 32; ++j) acc[j] = pvalid ? acc[j] : 0.f;  // pad = 0

    // depthwise k=3 via shuffles (lane i holds pre-conv at p0-1+i)
#pragma unroll
    for (int j = 0; j < 32; ++j) {
      const int ch = chbase + j;
      const float up = __shfl_up(acc[j], 1);
      const float dn = __shfl_down(acc[j], 1);
      acc[j] = fmaf(wdw[ch * 3 + 0], up,
               fmaf(wdw[ch * 3 + 1], acc[j], wdw[ch * 3 + 2] * dn));
    }
    if (lane >= 1 && lane <= 62) {
      const int l = lane - 1;
      const bool ok = (p0 + l) < LLEN;
      float* dst = dst_s + l * QS_PITCH + chbase;
#pragma unroll
      for (int j = 0; j < 32; ++j) dst[j] = ok ? acc[j] : 0.f;
    }
    __syncthreads();

    // ---- Gram accumulate over this tile's l-range
#pragma unroll 2
    for (int l = lbeg; l < lend; ++l) {
      const float4 qa = *(const float4*)&q_s[l * QS_PITCH + c0];
      const float4 qb = *(const float4*)&q_s[l * QS_PITCH + c0 + 4];
      const float4 kv = *(const float4*)&k_s[l * QS_PITCH + d0];
      const float qv[8] = {qa.x, qa.y, qa.z, qa.w, qb.x, qb.y, qb.z, qb.w};
      const float kk[4] = {kv.x, kv.y, kv.z, kv.w};
#pragma unroll
      for (int i = 0; i < 8; ++i)
#pragma unroll
        for (int j = 0; j < 4; ++j)
          gacc[i * 4 + j] = fmaf(qv[i], kk[j], gacc[i * 4 + j]);
    }
    // ---- norm partials: waves 0,2 = q; waves 1,3 = k
    {
      const float* nsrc = ((wv & 1) == 0) ? q_s : k_s;
#pragma unroll 2
      for (int l = lbeg; l < lend; ++l) {
        const float v = nsrc[l * QS_PITCH + lane];
        nrm = fmaf(v, v, nrm);
      }
    }
    __syncthreads();
  }

  // ---- cross-half reduction of Gram in LDS, then atomics
  float* scratch = smem;  // 128*33*4 = 16.9 KB, q_s/k_s dead
  if (tid >= 128) {
#pragma unroll
    for (int j = 0; j < 32; ++j) scratch[(tid - 128) * 33 + j] = gacc[j];
  }
  __syncthreads();
  if (tid < 128) {
    float* Gb = G + b * 4096;
#pragma unroll
    for (int j = 0; j < 32; ++j) {
      const float v = gacc[j] + scratch[tid * 33 + j];
      atomicAdd(&Gb[(c0 + (j >> 2)) * 64 + (d0 + (j & 3))], v);
    }
  }
  float* np = ((wv & 1) == 0) ? (nq + b * 64) : (nk + b * 64);
  atomicAdd(&np[lane], nrm);
}

// ---------------- Kernel B: logits -> softmax -> MT = (w_proj @ attn)^T -----
__global__ void attn_proj_kernel(const float* __restrict__ G,
                                 const float* __restrict__ nq,
                                 const float* __restrict__ nk,
                                 const float* __restrict__ w_proj,
                                 const float* __restrict__ temperature,
                                 float* __restrict__ MT) {
  __shared__ float attn_s[64][65];
  __shared__ float invq_s[64];
  __shared__ float invk_s[64];
  const int b = blockIdx.x;
  const int tid = threadIdx.x;
  if (tid < 64)       invq_s[tid]      = 1.f / fmaxf(sqrtf(nq[b * 64 + tid]), 1e-12f);
  else if (tid < 128) invk_s[tid - 64] = 1.f / fmaxf(sqrtf(nk[b * 64 + tid - 64]), 1e-12f);
  __syncthreads();
  const float temp = temperature[b];
  if (tid < 64) {
    const int c = tid;
    const float* Gr = G + b * 4096 + c * 64;
    const float iq = invq_s[c] * temp;
    float z[64];
    float m = -1e30f;
#pragma unroll
    for (int d = 0; d < 64; ++d) { z[d] = Gr[d] * iq * invk_s[d]; m = fmaxf(m, z[d]); }
    float s = 0.f;
#pragma unroll
    for (int d = 0; d < 64; ++d) { z[d] = expf(z[d] - m); s += z[d]; }
    const float inv = 1.f / s;
#pragma unroll
    for (int d = 0; d < 64; ++d) attn_s[c][d] = z[d] * inv;
  }
  __syncthreads();
  const int o = tid & 63;
  const int dg = tid >> 6;
  for (int d = dg * 16; d < dg * 16 + 16; ++d) {
    float s = 0.f;
#pragma unroll
    for (int c = 0; c < 64; ++c) s = fmaf(w_proj[o * 64 + c], attn_s[c][d], s);
    MT[b * 4096 + d * 64 + o] = s;   // transposed for kernel C's scalar loads
  }
}

// ---------------- Kernel C: v GEMM -> shuffle dwconv -> out = M @ v ---------
__global__ __launch_bounds__(256, 4) void out_kernel(
    const float* __restrict__ x, const float* __restrict__ wvT,
    const float* __restrict__ w_kv_dw, const float* __restrict__ MT,
    float* __restrict__ out) {
  __shared__ float v_s[64 * 64];   // [ch][l], 16 KB (cols 62,63 unused)

  const int tid  = threadIdx.x;
  const int lane = tid & 63;
  const int wv   = __builtin_amdgcn_readfirstlane(threadIdx.x >> 6);
  const int b    = blockIdx.y;

  const float* xb    = x + (size_t)b * CDIM * LLEN;
  const float* wv_dw = w_kv_dw + 192;       // v = rows 64..127
  const float* MTb   = MT + b * 4096;
  float* ob = out + (size_t)b * CDIM * LLEN;

  for (int ck = 0; ck < NCH_C; ++ck) {
    const int p0 = (blockIdx.x * NCH_C + ck) * TP;
    const int p  = p0 - 1 + lane;
    const int pc = min(max(p, 0), LLEN - 1);
    const bool pvalid = (p >= 0) && (p < LLEN);
    const float* xp = xb + pc;

    if (ck) __syncthreads();   // previous out-GEMM reads of v_s must finish

    // ---- v GEMM: 16 channels per wave, reg-pipelined x preload
    {
      const int ch0 = wv * 16;
      float acc[16];
#pragma unroll
      for (int j = 0; j < 16; ++j) acc[j] = 0.f;

      float xv[2][8];
#pragma unroll
      for (int i = 0; i < 8; ++i) xv[0][i] = xp[(size_t)i * LLEN];
#pragma unroll
      for (int chunk = 0; chunk < 8; ++chunk) {
        const int cur = chunk & 1;
        const int nxt = cur ^ 1;
        if (chunk < 7) {
#pragma unroll
          for (int i = 0; i < 8; ++i)
            xv[nxt][i] = xp[(size_t)((chunk + 1) * 8 + i) * LLEN];
        }
#pragma unroll
        for (int i = 0; i < 8; ++i) {
          const float xval = xv[cur][i];
          const float* wrow = wvT + (chunk * 8 + i) * 64 + ch0;  // s_load_dwordx16
#pragma unroll
          for (int j = 0; j < 16; ++j) acc[j] = fmaf(wrow[j], xval, acc[j]);
        }
      }
#pragma unroll
      for (int j = 0; j < 16; ++j) acc[j] = pvalid ? acc[j] : 0.f;
#pragma unroll
      for (int j = 0; j < 16; ++j) {
        const int ch = ch0 + j;
        const float up = __shfl_up(acc[j], 1);
        const float dn = __shfl_down(acc[j], 1);
        acc[j] = fmaf(wv_dw[ch * 3 + 0], up,
                 fmaf(wv_dw[ch * 3 + 1], acc[j], wv_dw[ch * 3 + 2] * dn));
      }
      if (lane >= 1 && lane <= 62) {
        const int l = lane - 1;
        const bool ok = (p0 + l) < LLEN;
#pragma unroll
        for (int j = 0; j < 16; ++j)
          v_s[(ch0 + j) * 64 + l] = ok ? acc[j] : 0.f;  // conflict-free stores
      }
    }
    __syncthreads();

    // ---- out GEMM: lane = position l, wave -> out channels wv*16..+15
    // v_s reads pipelined in 8-deep double-buffered register chunks.
    {
      const int l = lane;
      const int pp = p0 + l;
      const bool ok = (l < TP) && (pp < LLEN);
      const int o0 = wv * 16;
      float oacc[16];
#pragma unroll
      for (int j = 0; j < 16; ++j) oacc[j] = 0.f;

      float vv[2][8];
#pragma unroll
      for (int i = 0; i < 8; ++i) vv[0][i] = v_s[i * 64 + l];
#pragma unroll
      for (int chunk = 0; chunk < 8; ++chunk) {
        const int cur = chunk & 1;
        const int nxt = cur ^ 1;
        if (chunk < 7) {
#pragma unroll
          for (int i = 0; i < 8; ++i)
            vv[nxt][i] = v_s[((chunk + 1) * 8 + i) * 64 + l];
        }
#pragma unroll
        for (int i = 0; i < 8; ++i) {
          const float vvv = vv[cur][i];
          const float* mr = MTb + (chunk * 8 + i) * 64 + o0;  // s_load_dwordx16
#pragma unroll
          for (int j = 0; j < 16; ++j) oacc[j] = fmaf(mr[j], vvv, oacc[j]);
        }
      }
      if (ok) {
#pragma unroll
        for (int j = 0; j < 16; ++j)
          ob[(size_t)(o0 + j) * LLEN + pp] = oacc[j];
      }
    }
  }
}

extern "C" void kernel_launch(void* const* d_in, const int* in_sizes, int n_in,
                              void* d_out, int out_size, void* d_ws, size_t ws_size,
                              hipStream_t stream) {
  (void)in_sizes; (void)n_in; (void)out_size; (void)ws_size;
  const float* x           = (const float*)d_in[0];
  const float* w_kv        = (const float*)d_in[1];
  const float* w_kv_dw     = (const float*)d_in[2];
  const float* w_q         = (const float*)d_in[3];
  const float* w_q_dw      = (const float*)d_in[4];
  const float* w_proj      = (const float*)d_in[5];
  const float* temperature = (const float*)d_in[6];
  float* out = (float*)d_out;

  float* G   = (float*)d_ws;         // NB*4096
  float* nq  = G + NB * 4096;        // NB*64
  float* nk  = nq + NB * 64;         // NB*64
  float* MT  = nk + NB * 64;         // NB*4096
  float* wqT = MT + NB * 4096;       // 4096
  float* wkT = wqT + 4096;           // 4096
  float* wvT = wkT + 4096;           // 4096

  hipMemsetAsync(G, 0, (size_t)(NB * 4096 + 2 * NB * 64) * sizeof(float), stream);
  prep_kernel<<<dim3(16), dim3(256), 0, stream>>>(w_q, w_kv, wqT, wkT, wvT);
  qk_gram_kernel<<<dim3(BLKA, NB), dim3(256), 0, stream>>>(
      x, wqT, wkT, w_q_dw, w_kv_dw, G, nq, nk);
  attn_proj_kernel<<<dim3(NB), dim3(256), 0, stream>>>(
      G, nq, nk, w_proj, temperature, MT);
  out_kernel<<<dim3(BLKC, NB), dim3(256), 0, stream>>>(
      x, wvT, w_kv_dw, MT, out);
}

// Round 2
// 938.137 us; speedup vs baseline: 1.3025x; 1.3025x over previous
//
#include <hip/hip_runtime.h>

#define LLEN 131072
#define CDIM 64
#define NB 4
#define TP 62            // output positions per 64-wide window (1 halo each side)
#define NCH_A 3
#define BLKA 705         // 705*3 = 2115 tiles, 2115*62 = 131130 >= 131072
#define NCH_C 3
#define BLKC 705
#define QS_PITCH 68

// Async-stage one 64ch x 64pos x-tile into LDS (xs[ci][pos], 16 KB).
// Each wave stages 16 rows; per-lane global addr is clamped (halo garbage is
// zeroed later via pvalid). Width=4 avoids 16B-alignment issues (p0-1 is not
// 16B aligned). Completion is via the vmcnt(0) the compiler emits at the next
// __syncthreads().
__device__ __forceinline__ void stage_rows_async(const float* __restrict__ xb,
                                                 float* xs, int wv, int lane,
                                                 int p0) {
  const int p  = p0 - 1 + lane;
  const int pc = min(max(p, 0), LLEN - 1);
  const float* g0 = xb + pc;
#pragma unroll
  for (int k = 0; k < 16; ++k) {
    const int r = wv * 16 + k;
    __builtin_amdgcn_global_load_lds(
        (const __attribute__((address_space(1))) void*)(g0 + (size_t)r * LLEN),
        (__attribute__((address_space(3))) void*)(xs + r * 64), 4, 0, 0);
  }
}

// ---------------- prep: transposed weight tables (wT[ci][ch]) ----------------
__global__ void prep_kernel(const float* __restrict__ w_q,
                            const float* __restrict__ w_kv,
                            float* __restrict__ wqT, float* __restrict__ wkT,
                            float* __restrict__ wvT) {
  const int idx = blockIdx.x * 256 + threadIdx.x;  // 0..4095
  const int ci = idx >> 6, ch = idx & 63;
  wqT[ci * 64 + ch] = w_q[ch * 64 + ci];
  wkT[ci * 64 + ch] = w_kv[ch * 64 + ci];
  wvT[ci * 64 + ch] = w_kv[(64 + ch) * 64 + ci];
}

// ---------------- Kernel A: x staged in LDS -> qk GEMM -> shuffle dwconv
// ---------------- -> Gram (4x4 tile, full l) + norms ------------------------
__global__ __launch_bounds__(256, 3) void qk_gram_kernel(
    const float* __restrict__ x, const float* __restrict__ wqT,
    const float* __restrict__ wkT, const float* __restrict__ w_q_dw,
    const float* __restrict__ w_kv_dw, float* __restrict__ G,
    float* __restrict__ nq, float* __restrict__ nk) {
  __shared__ __attribute__((aligned(16))) float xs[64 * 64];            // 16 KB
  __shared__ __attribute__((aligned(16))) float smem[2 * TP * QS_PITCH]; // 33.7 KB
  float* q_s = smem;                       // [l][c], pitch 68
  float* k_s = smem + TP * QS_PITCH;

  const int tid  = threadIdx.x;
  const int lane = tid & 63;
  const int wv   = __builtin_amdgcn_readfirstlane(threadIdx.x >> 6);
  const int b    = blockIdx.y;

  const float* xb  = x + (size_t)b * CDIM * LLEN;
  const float* wT  = (wv < 2) ? wqT : wkT;
  const float* wdw = (wv < 2) ? w_q_dw : w_kv_dw;  // k = rows 0..63 of w_kv_dw
  const int chbase = (wv & 1) * 32;
  float* dst_s = (wv < 2) ? q_s : k_s;

  const int c0 = (tid & 15) * 4;   // Gram tile: 4x4, (c0, d0), all 256 threads
  const int d0 = (tid >> 4) * 4;   // cover the 64x64 Gram exactly once

  float gacc[16];
#pragma unroll
  for (int i = 0; i < 16; ++i) gacc[i] = 0.f;
  float nrm = 0.f;

  stage_rows_async(xb, xs, wv, lane, blockIdx.x * NCH_A * TP);
  __syncthreads();   // compiler drains vmcnt here -> xs ready

  for (int ck = 0; ck < NCH_A; ++ck) {
    const int p0 = (blockIdx.x * NCH_A + ck) * TP;
    const int p  = p0 - 1 + lane;
    const bool pvalid = (p >= 0) && (p < LLEN);

    // ---- GEMM: two passes of 16 channels per wave, x from LDS (low latency)
#pragma unroll
    for (int pass = 0; pass < 2; ++pass) {
      const int ch0 = chbase + pass * 16;
      float acc[16];
#pragma unroll
      for (int j = 0; j < 16; ++j) acc[j] = 0.f;
#pragma unroll 4
      for (int ci = 0; ci < 64; ++ci) {
        const float xv = xs[ci * 64 + lane];        // ds_read_b32, conflict-free
        const float* wrow = wT + ci * 64 + ch0;     // s_load_dwordx16
#pragma unroll
        for (int j = 0; j < 16; ++j) acc[j] = fmaf(wrow[j], xv, acc[j]);
      }
#pragma unroll
      for (int j = 0; j < 16; ++j) acc[j] = pvalid ? acc[j] : 0.f;  // pad = 0
      // depthwise k=3 via shuffles (lane i holds pre-conv at p0-1+i)
#pragma unroll
      for (int j = 0; j < 16; ++j) {
        const int ch = ch0 + j;
        const float up = __shfl_up(acc[j], 1);
        const float dn = __shfl_down(acc[j], 1);
        acc[j] = fmaf(wdw[ch * 3 + 0], up,
                 fmaf(wdw[ch * 3 + 1], acc[j], wdw[ch * 3 + 2] * dn));
      }
      if (lane >= 1 && lane <= 62) {
        const int l = lane - 1;
        const bool ok = (p0 + l) < LLEN;
        float* dst = dst_s + l * QS_PITCH + ch0;
#pragma unroll
        for (int j = 0; j < 16; ++j) dst[j] = ok ? acc[j] : 0.f;
      }
    }
    __syncthreads();   // q_s/k_s visible; all xs reads of this window done

    // issue next window's x stage now; Gram below (~2k cycles) hides HBM latency
    if (ck + 1 < NCH_A)
      stage_rows_async(xb, xs, wv, lane, (blockIdx.x * NCH_A + ck + 1) * TP);

    // ---- Gram accumulate, full l-range, 4x4 tile per thread
#pragma unroll 2
    for (int l = 0; l < TP; ++l) {
      const float4 qv4 = *(const float4*)&q_s[l * QS_PITCH + c0];
      const float4 kv4 = *(const float4*)&k_s[l * QS_PITCH + d0];
      const float qv[4] = {qv4.x, qv4.y, qv4.z, qv4.w};
      const float kk[4] = {kv4.x, kv4.y, kv4.z, kv4.w};
#pragma unroll
      for (int i = 0; i < 4; ++i)
#pragma unroll
        for (int j = 0; j < 4; ++j)
          gacc[i * 4 + j] = fmaf(qv[i], kk[j], gacc[i * 4 + j]);
    }
    // ---- norm partials: src by wv&1 (q/k), l-half by wv>>1
    {
      const float* nsrc = ((wv & 1) == 0) ? q_s : k_s;
      const int nl0 = (wv >> 1) ? 31 : 0;
      const int nl1 = (wv >> 1) ? TP : 31;
#pragma unroll 2
      for (int l = nl0; l < nl1; ++l) {
        const float v = nsrc[l * QS_PITCH + lane];
        nrm = fmaf(v, v, nrm);
      }
    }
    __syncthreads();   // drains stage vmcnt; protects q_s/k_s for next window
  }

  // ---- direct atomics: each thread owns its 4x4 Gram tile over full l
  float* Gb = G + b * 4096;
#pragma unroll
  for (int j = 0; j < 16; ++j)
    atomicAdd(&Gb[(c0 + (j >> 2)) * 64 + (d0 + (j & 3))], gacc[j]);
  float* np = ((wv & 1) == 0) ? (nq + b * 64) : (nk + b * 64);
  atomicAdd(&np[lane], nrm);
}

// ---------------- Kernel B: logits -> softmax -> MT = (w_proj @ attn)^T -----
__global__ void attn_proj_kernel(const float* __restrict__ G,
                                 const float* __restrict__ nq,
                                 const float* __restrict__ nk,
                                 const float* __restrict__ w_proj,
                                 const float* __restrict__ temperature,
                                 float* __restrict__ MT) {
  __shared__ float attn_s[64][65];
  __shared__ float invq_s[64];
  __shared__ float invk_s[64];
  const int b = blockIdx.x;
  const int tid = threadIdx.x;
  if (tid < 64)       invq_s[tid]      = 1.f / fmaxf(sqrtf(nq[b * 64 + tid]), 1e-12f);
  else if (tid < 128) invk_s[tid - 64] = 1.f / fmaxf(sqrtf(nk[b * 64 + tid - 64]), 1e-12f);
  __syncthreads();
  const float temp = temperature[b];
  if (tid < 64) {
    const int c = tid;
    const float* Gr = G + b * 4096 + c * 64;
    const float iq = invq_s[c] * temp;
    float z[64];
    float m = -1e30f;
#pragma unroll
    for (int d = 0; d < 64; ++d) { z[d] = Gr[d] * iq * invk_s[d]; m = fmaxf(m, z[d]); }
    float s = 0.f;
#pragma unroll
    for (int d = 0; d < 64; ++d) { z[d] = expf(z[d] - m); s += z[d]; }
    const float inv = 1.f / s;
#pragma unroll
    for (int d = 0; d < 64; ++d) attn_s[c][d] = z[d] * inv;
  }
  __syncthreads();
  const int o = tid & 63;
  const int dg = tid >> 6;
  for (int d = dg * 16; d < dg * 16 + 16; ++d) {
    float s = 0.f;
#pragma unroll
    for (int c = 0; c < 64; ++c) s = fmaf(w_proj[o * 64 + c], attn_s[c][d], s);
    MT[b * 4096 + d * 64 + o] = s;   // transposed for kernel C's scalar loads
  }
}

// ---------------- Kernel C: x staged in LDS -> v GEMM -> shuffle dwconv
// ---------------- -> out = M @ v --------------------------------------------
__global__ __launch_bounds__(256, 5) void out_kernel(
    const float* __restrict__ x, const float* __restrict__ wvT,
    const float* __restrict__ w_kv_dw, const float* __restrict__ MT,
    float* __restrict__ out) {
  __shared__ __attribute__((aligned(16))) float xs[64 * 64];   // 16 KB
  __shared__ __attribute__((aligned(16))) float v_s[64 * 64];  // 16 KB [ch][l]

  const int tid  = threadIdx.x;
  const int lane = tid & 63;
  const int wv   = __builtin_amdgcn_readfirstlane(threadIdx.x >> 6);
  const int b    = blockIdx.y;

  const float* xb    = x + (size_t)b * CDIM * LLEN;
  const float* wv_dw = w_kv_dw + 192;       // v = rows 64..127
  const float* MTb   = MT + b * 4096;
  float* ob = out + (size_t)b * CDIM * LLEN;

  stage_rows_async(xb, xs, wv, lane, blockIdx.x * NCH_C * TP);
  __syncthreads();

  for (int ck = 0; ck < NCH_C; ++ck) {
    const int p0 = (blockIdx.x * NCH_C + ck) * TP;
    const int p  = p0 - 1 + lane;
    const bool pvalid = (p >= 0) && (p < LLEN);

    // ---- v GEMM: 16 channels per wave, x from LDS
    {
      const int ch0 = wv * 16;
      float acc[16];
#pragma unroll
      for (int j = 0; j < 16; ++j) acc[j] = 0.f;
#pragma unroll 4
      for (int ci = 0; ci < 64; ++ci) {
        const float xv = xs[ci * 64 + lane];        // ds_read_b32, conflict-free
        const float* wrow = wvT + ci * 64 + ch0;    // s_load_dwordx16
#pragma unroll
        for (int j = 0; j < 16; ++j) acc[j] = fmaf(wrow[j], xv, acc[j]);
      }
#pragma unroll
      for (int j = 0; j < 16; ++j) acc[j] = pvalid ? acc[j] : 0.f;
#pragma unroll
      for (int j = 0; j < 16; ++j) {
        const int ch = ch0 + j;
        const float up = __shfl_up(acc[j], 1);
        const float dn = __shfl_down(acc[j], 1);
        acc[j] = fmaf(wv_dw[ch * 3 + 0], up,
                 fmaf(wv_dw[ch * 3 + 1], acc[j], wv_dw[ch * 3 + 2] * dn));
      }
      if (lane >= 1 && lane <= 62) {
        const int l = lane - 1;
        const bool ok = (p0 + l) < LLEN;
#pragma unroll
        for (int j = 0; j < 16; ++j)
          v_s[(ch0 + j) * 64 + l] = ok ? acc[j] : 0.f;  // conflict-free stores
      }
    }
    __syncthreads();   // v_s ready; all xs reads of this window done

    // issue next window's x stage; out-GEMM below hides the latency
    if (ck + 1 < NCH_C)
      stage_rows_async(xb, xs, wv, lane, (blockIdx.x * NCH_C + ck + 1) * TP);

    // ---- out GEMM: lane = position l, wave -> out channels wv*16..+15
    {
      const int l = lane;
      const int pp = p0 + l;
      const bool ok = (l < TP) && (pp < LLEN);
      const int o0 = wv * 16;
      float oacc[16];
#pragma unroll
      for (int j = 0; j < 16; ++j) oacc[j] = 0.f;
#pragma unroll 4
      for (int d = 0; d < 64; ++d) {
        const float vvv = v_s[d * 64 + l];         // conflict-free
        const float* mr = MTb + d * 64 + o0;       // s_load_dwordx16
#pragma unroll
        for (int j = 0; j < 16; ++j) oacc[j] = fmaf(mr[j], vvv, oacc[j]);
      }
      if (ok) {
#pragma unroll
        for (int j = 0; j < 16; ++j)
          ob[(size_t)(o0 + j) * LLEN + pp] = oacc[j];
      }
    }
    __syncthreads();   // drains stage vmcnt; protects v_s for next window
  }
}

extern "C" void kernel_launch(void* const* d_in, const int* in_sizes, int n_in,
                              void* d_out, int out_size, void* d_ws, size_t ws_size,
                              hipStream_t stream) {
  (void)in_sizes; (void)n_in; (void)out_size; (void)ws_size;
  const float* x           = (const float*)d_in[0];
  const float* w_kv        = (const float*)d_in[1];
  const float* w_kv_dw     = (const float*)d_in[2];
  const float* w_q         = (const float*)d_in[3];
  const float* w_q_dw      = (const float*)d_in[4];
  const float* w_proj      = (const float*)d_in[5];
  const float* temperature = (const float*)d_in[6];
  float* out = (float*)d_out;

  float* G   = (float*)d_ws;         // NB*4096
  float* nq  = G + NB * 4096;        // NB*64
  float* nk  = nq + NB * 64;         // NB*64
  float* MT  = nk + NB * 64;         // NB*4096
  float* wqT = MT + NB * 4096;       // 4096
  float* wkT = wqT + 4096;           // 4096
  float* wvT = wkT + 4096;           // 4096

  hipMemsetAsync(G, 0, (size_t)(NB * 4096 + 2 * NB * 64) * sizeof(float), stream);
  prep_kernel<<<dim3(16), dim3(256), 0, stream>>>(w_q, w_kv, wqT, wkT, wvT);
  qk_gram_kernel<<<dim3(BLKA, NB), dim3(256), 0, stream>>>(
      x, wqT, wkT, w_q_dw, w_kv_dw, G, nq, nk);
  attn_proj_kernel<<<dim3(NB), dim3(256), 0, stream>>>(
      G, nq, nk, w_proj, temperature, MT);
  out_kernel<<<dim3(BLKC, NB), dim3(256), 0, stream>>>(
      x, wvT, w_kv_dw, MT, out);
}

// Round 4
// 412.646 us; speedup vs baseline: 2.9613x; 2.2735x over previous
//
#include <hip/hip_runtime.h>

#define LLEN 131072
#define CDIM 64
#define NB 4
#define TP 62            // output positions per 64-wide window (1 halo each side)
#define NCH_A 5
#define BLKA 423         // 423*5 = 2115 windows, 2115*62 = 131130 >= 131072
#define NCH_C 5
#define BLKC 423
#define XSP 65           // xs pitch (floats): 65 -> stride-65 column reads conflict-free
#define QHP 72           // qh/kh/vh pitch (halves): rows 144B (16B aligned)

typedef _Float16 half8 __attribute__((ext_vector_type(8)));
typedef float f32x4 __attribute__((ext_vector_type(4)));
#define MFMA16 __builtin_amdgcn_mfma_f32_16x16x32_f16

// ---- cross-lane helpers (16-lane groups) ----
__device__ __forceinline__ float dpp_shr1(float v) {  // dst[c] = src[c-1], c==0 -> 0
  return __int_as_float(__builtin_amdgcn_update_dpp(
      0, __float_as_int(v), 0x111, 0xF, 0xF, true));
}
__device__ __forceinline__ float dpp_shl1(float v) {  // dst[c] = src[c+1], c==15 -> 0
  return __int_as_float(__builtin_amdgcn_update_dpp(
      0, __float_as_int(v), 0x101, 0xF, 0xF, true));
}
template <int PAT>
__device__ __forceinline__ float swz(float v) {       // pattern must be constexpr
  return __int_as_float(__builtin_amdgcn_ds_swizzle(__float_as_int(v), PAT));
}
#define SWZ_BC15 0x1F0   // every lane <- lane of its 16-group with c==15
#define SWZ_BC0  0x010   // every lane <- lane of its 16-group with c==0

// depthwise k=3 conv across positions, on 4 D-frags (pos = n*16+c), in place.
// dwt[t*4+r] = per-lane coeffs for its 4 channels (r).
__device__ __forceinline__ void conv3(f32x4 a[4], const float* dwt, int c) {
  f32x4 o[4];
#pragma unroll
  for (int n = 0; n < 4; ++n) {
#pragma unroll
    for (int r = 0; r < 4; ++r) {
      const float cur = a[n][r];
      float lf = dpp_shr1(cur);
      const float lb = (n > 0) ? swz<SWZ_BC15>(a[n - 1][r]) : 0.f;
      lf = (c == 0) ? lb : lf;
      float rt = dpp_shl1(cur);
      const float rb = (n < 3) ? swz<SWZ_BC0>(a[n + 1][r]) : 0.f;
      rt = (c == 15) ? rb : rt;
      o[n][r] = dwt[0 * 4 + r] * lf + dwt[1 * 4 + r] * cur + dwt[2 * 4 + r] * rt;
    }
  }
#pragma unroll
  for (int n = 0; n < 4; ++n) a[n] = o[n];
}

// async-stage one 64ch x 64pos f32 x-tile into LDS xs[ci][pos] (pitch XSP)
__device__ __forceinline__ void stage_x(const float* __restrict__ xb,
                                        float* xs, int wv, int lane, int w0) {
  const int p = w0 - 1 + lane;
  const int pc = min(max(p, 0), LLEN - 1);
  const float* g0 = xb + pc;
#pragma unroll
  for (int k = 0; k < 16; ++k) {
    const int r = wv * 16 + k;
    __builtin_amdgcn_global_load_lds(
        (const __attribute__((address_space(1))) void*)(g0 + (size_t)r * LLEN),
        (__attribute__((address_space(3))) void*)(xs + r * XSP), 4, 0, 0);
  }
}

// ---------------- prep: f16 A-fragment weight tables --------------------------
// table idx = ((m*2+ks)*64 + lane)*8 + j  ->  W[ch = m*16+(lane&15)][ci = ks*32+((lane>>4)&3)*8+j]
__global__ void prep_kernel(const float* __restrict__ w_q,
                            const float* __restrict__ w_kv,
                            _Float16* __restrict__ wqA, _Float16* __restrict__ wkA,
                            _Float16* __restrict__ wvA) {
  const int t = blockIdx.x * 256 + threadIdx.x;  // 0..4095
  const int j = t & 7;
  const int row = t >> 3;          // 0..511
  const int lane = row & 63;
  const int frag = row >> 6;       // m*2+ks
  const int m = frag >> 1, ks = frag & 1;
  const int ch = m * 16 + (lane & 15);
  const int ci = ks * 32 + ((lane >> 4) & 3) * 8 + j;
  wqA[t] = (_Float16)w_q[ch * 64 + ci];
  wkA[t] = (_Float16)w_kv[ch * 64 + ci];
  wvA[t] = (_Float16)w_kv[(64 + ch) * 64 + ci];
}

// ---------------- Kernel A: MFMA q/k GEMM -> DPP dwconv -> MFMA Gram ---------
__global__ __launch_bounds__(256) void qk_gram_kernel(
    const float* __restrict__ x, const _Float16* __restrict__ wqA,
    const _Float16* __restrict__ wkA, const float* __restrict__ w_q_dw,
    const float* __restrict__ w_kv_dw, float* __restrict__ G,
    float* __restrict__ nq, float* __restrict__ nk) {
  __shared__ __attribute__((aligned(16))) float xs[64 * XSP];       // 16.6 KB
  __shared__ __attribute__((aligned(16))) _Float16 qh[64 * QHP];    // 9.2 KB
  __shared__ __attribute__((aligned(16))) _Float16 kh[64 * QHP];    // 9.2 KB

  const int tid  = threadIdx.x;
  const int lane = tid & 63;
  const int wv   = __builtin_amdgcn_readfirstlane(tid >> 6);
  const int g    = lane >> 4;       // 0..3
  const int c    = lane & 15;       // 0..15
  const int b    = blockIdx.y;

  const float* xb = x + (size_t)b * CDIM * LLEN;

  // persistent A-frags (weights) and conv coeffs
  half8 aQ[2], aK[2];
#pragma unroll
  for (int ks = 0; ks < 2; ++ks) {
    aQ[ks] = *(const half8*)(wqA + ((wv * 2 + ks) * 64 + lane) * 8);
    aK[ks] = *(const half8*)(wkA + ((wv * 2 + ks) * 64 + lane) * 8);
  }
  float dwq[12], dwk[12];
#pragma unroll
  for (int r = 0; r < 4; ++r) {
    const int ch = wv * 16 + g * 4 + r;
#pragma unroll
    for (int t = 0; t < 3; ++t) {
      dwq[t * 4 + r] = w_q_dw[ch * 3 + t];
      dwk[t * 4 + r] = w_kv_dw[ch * 3 + t];   // k = rows 0..63 of w_kv_dw
    }
  }

  f32x4 gacc[4];          // Gram: rows m*16+g*4+r, col wv*16+c (accum all windows)
#pragma unroll
  for (int m = 0; m < 4; ++m)
#pragma unroll
    for (int r = 0; r < 4; ++r) gacc[m][r] = 0.f;
  float nrmq[4] = {0.f, 0.f, 0.f, 0.f}, nrmk[4] = {0.f, 0.f, 0.f, 0.f};

  stage_x(xb, xs, wv, lane, blockIdx.x * NCH_A * TP);
  __syncthreads();   // xs(0) ready (compiler drains vmcnt before barrier)

  for (int ck = 0; ck < NCH_A; ++ck) {
    const int w0 = (blockIdx.x * NCH_A + ck) * TP;

    // ---- q/k GEMM: D row = out-ch (wv quarter), col = pos
    f32x4 qacc[4], kacc[4];
#pragma unroll
    for (int n = 0; n < 4; ++n)
#pragma unroll
      for (int r = 0; r < 4; ++r) { qacc[n][r] = 0.f; kacc[n][r] = 0.f; }

#pragma unroll
    for (int ks = 0; ks < 2; ++ks) {
      half8 bf[4];
#pragma unroll
      for (int n = 0; n < 4; ++n) {
        const float* xcol = xs + (ks * 32 + g * 8) * XSP + n * 16 + c;
#pragma unroll
        for (int j = 0; j < 8; ++j) bf[n][j] = (_Float16)xcol[j * XSP];
      }
#pragma unroll
      for (int n = 0; n < 4; ++n) {
        qacc[n] = MFMA16(aQ[ks], bf[n], qacc[n], 0, 0, 0);
        kacc[n] = MFMA16(aK[ks], bf[n], kacc[n], 0, 0, 0);
      }
    }

    // ---- zero-pad invalid positions (matches zero padding), then conv
#pragma unroll
    for (int n = 0; n < 4; ++n) {
      const int P = w0 - 1 + n * 16 + c;
      const bool pv = (P >= 0) && (P < LLEN);
#pragma unroll
      for (int r = 0; r < 4; ++r) {
        qacc[n][r] = pv ? qacc[n][r] : 0.f;
        kacc[n][r] = pv ? kacc[n][r] : 0.f;
      }
    }
    conv3(qacc, dwq, c);
    conv3(kacc, dwk, c);

    __syncthreads();   // S1: Gram(w-1) reads of qh/kh complete

    // ---- round to f16 (norms from the SAME rounded values), store to LDS
#pragma unroll
    for (int n = 0; n < 4; ++n) {
      const int pos = n * 16 + c;
      const bool ok = (pos >= 1) && (pos <= 62) && (w0 - 1 + pos < LLEN);
#pragma unroll
      for (int r = 0; r < 4; ++r) {
        const _Float16 hq = ok ? (_Float16)qacc[n][r] : (_Float16)0.f;
        const _Float16 hk = ok ? (_Float16)kacc[n][r] : (_Float16)0.f;
        const float fq = (float)hq, fk = (float)hk;
        nrmq[r] = fmaf(fq, fq, nrmq[r]);
        nrmk[r] = fmaf(fk, fk, nrmk[r]);
        qh[(wv * 16 + g * 4 + r) * QHP + pos] = hq;
        kh[(wv * 16 + g * 4 + r) * QHP + pos] = hk;
      }
    }

    if (ck + 1 < NCH_A)
      stage_x(xb, xs, wv, lane, (blockIdx.x * NCH_A + ck + 1) * TP);

    __syncthreads();   // S2: qh/kh ready

    // ---- Gram: G += Q * K^T over this window's 64 (zero-padded) positions
    {
      const _Float16* kcol = kh + (wv * 16 + c) * QHP + g * 8;
      const half8 bK0 = *(const half8*)(kcol);
      const half8 bK1 = *(const half8*)(kcol + 32);
#pragma unroll
      for (int m = 0; m < 4; ++m) {
        const _Float16* qrow = qh + (m * 16 + c) * QHP + g * 8;
        const half8 a0 = *(const half8*)(qrow);
        const half8 a1 = *(const half8*)(qrow + 32);
        gacc[m] = MFMA16(a0, bK0, gacc[m], 0, 0, 0);
        gacc[m] = MFMA16(a1, bK1, gacc[m], 0, 0, 0);
      }
    }
    __syncthreads();   // S0': drains stage vmcnt; protects qh/kh reads
  }

  // ---- finalize: G atomics (one per element per block), norm reduce+atomics
  float* Gb = G + b * 4096;
#pragma unroll
  for (int m = 0; m < 4; ++m)
#pragma unroll
    for (int r = 0; r < 4; ++r)
      atomicAdd(&Gb[(m * 16 + g * 4 + r) * 64 + wv * 16 + c], gacc[m][r]);

#pragma unroll
  for (int r = 0; r < 4; ++r) {
    nrmq[r] += __shfl_xor(nrmq[r], 1);  nrmk[r] += __shfl_xor(nrmk[r], 1);
    nrmq[r] += __shfl_xor(nrmq[r], 2);  nrmk[r] += __shfl_xor(nrmk[r], 2);
    nrmq[r] += __shfl_xor(nrmq[r], 4);  nrmk[r] += __shfl_xor(nrmk[r], 4);
    nrmq[r] += __shfl_xor(nrmq[r], 8);  nrmk[r] += __shfl_xor(nrmk[r], 8);
  }
  if (c == 0) {
#pragma unroll
    for (int r = 0; r < 4; ++r) {
      atomicAdd(&nq[b * 64 + wv * 16 + g * 4 + r], nrmq[r]);
      atomicAdd(&nk[b * 64 + wv * 16 + g * 4 + r], nrmk[r]);
    }
  }
}

// ---------------- Kernel B: softmax -> M = w_proj@attn -> f16 A-frag table ---
__global__ void attn_proj_kernel(const float* __restrict__ G,
                                 const float* __restrict__ nq,
                                 const float* __restrict__ nk,
                                 const float* __restrict__ w_proj,
                                 const float* __restrict__ temperature,
                                 _Float16* __restrict__ Mh) {
  __shared__ float attn_s[64][65];
  __shared__ float Ms[64][65];
  __shared__ float invq_s[64];
  __shared__ float invk_s[64];
  const int b = blockIdx.x;
  const int tid = threadIdx.x;
  if (tid < 64)       invq_s[tid]      = 1.f / fmaxf(sqrtf(nq[b * 64 + tid]), 1e-12f);
  else if (tid < 128) invk_s[tid - 64] = 1.f / fmaxf(sqrtf(nk[b * 64 + tid - 64]), 1e-12f);
  __syncthreads();
  const float temp = temperature[b];
  if (tid < 64) {
    const int cq = tid;
    const float* Gr = G + b * 4096 + cq * 64;
    const float iq = invq_s[cq] * temp;
    float z[64];
    float m = -1e30f;
#pragma unroll
    for (int d = 0; d < 64; ++d) { z[d] = Gr[d] * iq * invk_s[d]; m = fmaxf(m, z[d]); }
    float s = 0.f;
#pragma unroll
    for (int d = 0; d < 64; ++d) { z[d] = expf(z[d] - m); s += z[d]; }
    const float inv = 1.f / s;
#pragma unroll
    for (int d = 0; d < 64; ++d) attn_s[cq][d] = z[d] * inv;
  }
  __syncthreads();
  const int o = tid & 63;
  const int dg = tid >> 6;
  for (int d = dg * 16; d < dg * 16 + 16; ++d) {
    float s = 0.f;
#pragma unroll
    for (int cc = 0; cc < 64; ++cc) s = fmaf(w_proj[o * 64 + cc], attn_s[cc][d], s);
    Ms[o][d] = s;
  }
  __syncthreads();
  // write M as f16 A-frag table: ((m*2+ks)*64+lane)*8+j
  for (int e = tid; e < 512; e += 256) {
    const int lane_ = e & 63, frag = e >> 6;
    const int m = frag >> 1, ks = frag & 1;
    const int o_ = m * 16 + (lane_ & 15);
    const int d0 = ks * 32 + ((lane_ >> 4) & 3) * 8;
    _Float16* dst = Mh + b * 4096 + e * 8;
#pragma unroll
    for (int j = 0; j < 8; ++j) dst[j] = (_Float16)Ms[o_][d0 + j];
  }
}

// ---------------- Kernel C: MFMA v GEMM -> conv -> out = M@V via MFMA --------
__global__ __launch_bounds__(256) void out_kernel(
    const float* __restrict__ x, const _Float16* __restrict__ wvA,
    const float* __restrict__ w_kv_dw, const _Float16* __restrict__ Mh,
    float* __restrict__ out) {
  __shared__ __attribute__((aligned(16))) float xs[64 * XSP];     // 16.6 KB
  __shared__ __attribute__((aligned(16))) _Float16 vh[64 * QHP];  // [pos][d], 9.2 KB

  const int tid  = threadIdx.x;
  const int lane = tid & 63;
  const int wv   = __builtin_amdgcn_readfirstlane(tid >> 6);
  const int g    = lane >> 4;
  const int c    = lane & 15;
  const int b    = blockIdx.y;

  const float* xb = x + (size_t)b * CDIM * LLEN;
  float* ob = out + (size_t)b * CDIM * LLEN;

  half8 aV[2], aM[2];
#pragma unroll
  for (int ks = 0; ks < 2; ++ks) {
    aV[ks] = *(const half8*)(wvA + ((wv * 2 + ks) * 64 + lane) * 8);
    aM[ks] = *(const half8*)(Mh + b * 4096 + ((wv * 2 + ks) * 64 + lane) * 8);
  }
  float dwv[12];
#pragma unroll
  for (int r = 0; r < 4; ++r) {
    const int ch = wv * 16 + g * 4 + r;
#pragma unroll
    for (int t = 0; t < 3; ++t) dwv[t * 4 + r] = w_kv_dw[(64 + ch) * 3 + t];
  }

  stage_x(xb, xs, wv, lane, blockIdx.x * NCH_C * TP);
  __syncthreads();

  for (int ck = 0; ck < NCH_C; ++ck) {
    const int w0 = (blockIdx.x * NCH_C + ck) * TP;

    // ---- v GEMM (wv's channel quarter)
    f32x4 vacc[4];
#pragma unroll
    for (int n = 0; n < 4; ++n)
#pragma unroll
      for (int r = 0; r < 4; ++r) vacc[n][r] = 0.f;

#pragma unroll
    for (int ks = 0; ks < 2; ++ks) {
      half8 bf[4];
#pragma unroll
      for (int n = 0; n < 4; ++n) {
        const float* xcol = xs + (ks * 32 + g * 8) * XSP + n * 16 + c;
#pragma unroll
        for (int j = 0; j < 8; ++j) bf[n][j] = (_Float16)xcol[j * XSP];
      }
#pragma unroll
      for (int n = 0; n < 4; ++n)
        vacc[n] = MFMA16(aV[ks], bf[n], vacc[n], 0, 0, 0);
    }

#pragma unroll
    for (int n = 0; n < 4; ++n) {
      const int P = w0 - 1 + n * 16 + c;
      const bool pv = (P >= 0) && (P < LLEN);
#pragma unroll
      for (int r = 0; r < 4; ++r) vacc[n][r] = pv ? vacc[n][r] : 0.f;
    }
    conv3(vacc, dwv, c);

    __syncthreads();   // S1: out-GEMM(w-1) reads of vh complete

    // vh[pos][d] (pos-major: out-GEMM contracts over d)
#pragma unroll
    for (int n = 0; n < 4; ++n) {
      const int pos = n * 16 + c;
      const bool ok = (pos >= 1) && (pos <= 62) && (w0 - 1 + pos < LLEN);
#pragma unroll
      for (int r = 0; r < 4; ++r) {
        const _Float16 hv = ok ? (_Float16)vacc[n][r] : (_Float16)0.f;
        vh[pos * QHP + wv * 16 + g * 4 + r] = hv;
      }
    }

    if (ck + 1 < NCH_C)
      stage_x(xb, xs, wv, lane, (blockIdx.x * NCH_C + ck + 1) * TP);

    __syncthreads();   // S2: vh ready

    // ---- out GEMM: rows o (wv quarter), cols pos, contract d
    f32x4 oacc[4];
#pragma unroll
    for (int n = 0; n < 4; ++n)
#pragma unroll
      for (int r = 0; r < 4; ++r) oacc[n][r] = 0.f;
#pragma unroll
    for (int n = 0; n < 4; ++n) {
      const _Float16* vrow = vh + (n * 16 + c) * QHP + g * 8;
      const half8 b0 = *(const half8*)(vrow);
      const half8 b1 = *(const half8*)(vrow + 32);
      oacc[n] = MFMA16(aM[0], b0, oacc[n], 0, 0, 0);
      oacc[n] = MFMA16(aM[1], b1, oacc[n], 0, 0, 0);
    }
#pragma unroll
    for (int n = 0; n < 4; ++n) {
      const int pos = n * 16 + c;
      const int P = w0 - 1 + pos;
      if (pos >= 1 && pos <= 62 && P < LLEN) {
#pragma unroll
        for (int r = 0; r < 4; ++r)
          ob[(size_t)(wv * 16 + g * 4 + r) * LLEN + P] = oacc[n][r];
      }
    }
    __syncthreads();   // S0': drains stage vmcnt; protects vh reads
  }
}

extern "C" void kernel_launch(void* const* d_in, const int* in_sizes, int n_in,
                              void* d_out, int out_size, void* d_ws, size_t ws_size,
                              hipStream_t stream) {
  (void)in_sizes; (void)n_in; (void)out_size; (void)ws_size;
  const float* x           = (const float*)d_in[0];
  const float* w_kv        = (const float*)d_in[1];
  const float* w_kv_dw     = (const float*)d_in[2];
  const float* w_q         = (const float*)d_in[3];
  const float* w_q_dw      = (const float*)d_in[4];
  const float* w_proj      = (const float*)d_in[5];
  const float* temperature = (const float*)d_in[6];
  float* out = (float*)d_out;

  float* G   = (float*)d_ws;            // 16384 f32
  float* nqp = G + 16384;               // 256
  float* nkp = nqp + 256;               // 256
  _Float16* Mh  = (_Float16*)(nkp + 256);  // 4*4096 halves
  _Float16* wqA = Mh + NB * 4096;       // 4096 halves each
  _Float16* wkA = wqA + 4096;
  _Float16* wvA = wkA + 4096;

  (void)hipMemsetAsync(G, 0, (size_t)(16384 + 512) * sizeof(float), stream);
  prep_kernel<<<dim3(16), dim3(256), 0, stream>>>(w_q, w_kv, wqA, wkA, wvA);
  qk_gram_kernel<<<dim3(BLKA, NB), dim3(256), 0, stream>>>(
      x, wqA, wkA, w_q_dw, w_kv_dw, G, nqp, nkp);
  attn_proj_kernel<<<dim3(NB), dim3(256), 0, stream>>>(
      G, nqp, nkp, w_proj, temperature, Mh);
  out_kernel<<<dim3(BLKC, NB), dim3(256), 0, stream>>>(
      x, wvA, w_kv_dw, Mh, out);
}